// Round 15
// baseline (85.413 us; speedup 1.0000x reference)
//
#include <hip/hip_runtime.h>
#include <hip/hip_bf16.h>
#include <math.h>

#define B_ 4
#define T_ 4096
#define C_ 1024
#define H_ 64
#define ROWS_ (B_*T_)

typedef __attribute__((ext_vector_type(8))) short bf16x8;
typedef __attribute__((ext_vector_type(4))) float f32x4;

__device__ __forceinline__ unsigned short f2bf(float f) {
    union { float f; unsigned u; } x; x.f = f;
    unsigned r = x.u + 0x7fffu + ((x.u >> 16) & 1u);   // RNE
    return (unsigned short)(r >> 16);
}
__device__ __forceinline__ float bf2f(unsigned short s) {
    union { unsigned u; float f; } x; x.u = ((unsigned)s) << 16;
    return x.f;
}
__device__ __forceinline__ unsigned pk2bf(float a, float b) {
    __hip_bfloat162 h = __float22bfloat162_rn(float2{a, b});
    return *reinterpret_cast<unsigned*>(&h);
}
// async global->LDS DMA, 16B/lane.
__device__ __forceinline__ void gld16(const void* g, void* l) {
    __builtin_amdgcn_global_load_lds(
        (const __attribute__((address_space(1))) unsigned*)g,
        (__attribute__((address_space(3))) unsigned*)l, 16, 0, 0);
}

// ---------------------------------------------------------------------------
// Kernel 0: fused weight prep (blocks 0..47) + RoPE table (blocks 48..559).
// ---------------------------------------------------------------------------
__global__ __launch_bounds__(256) void prep_kernel(
    const float* __restrict__ wq, const float* __restrict__ wk,
    const float* __restrict__ wv, unsigned short* __restrict__ wt,
    float* __restrict__ tab)
{
    __shared__ float ts[64][68];
    const int tid = threadIdx.x;
    if (blockIdx.x < 48) {
        const int m  = blockIdx.x >> 4;
        const int k0 = (blockIdx.x & 15) * 64;
        const float* w = (m == 0) ? wq : (m == 1) ? wk : wv;
        {
            const int r = tid >> 2;
            const int c = (tid & 3) * 16;
            #pragma unroll
            for (int i = 0; i < 4; ++i)
                *reinterpret_cast<float4*>(&ts[r][c + 4*i]) =
                    *reinterpret_cast<const float4*>(&w[(size_t)(k0 + r)*H_ + c + 4*i]);
        }
        __syncthreads();
        {
            const int n  = tid >> 2;
            const int kc = (tid & 3) * 16;
            unsigned short outp[16];
            #pragma unroll
            for (int j = 0; j < 16; ++j) outp[j] = f2bf(ts[kc + j][n]);
            unsigned short* dst = &wt[((size_t)m*64 + n)*C_ + k0 + kc];
            *reinterpret_cast<uint4*>(dst)     = *reinterpret_cast<uint4*>(&outp[0]);
            *reinterpret_cast<uint4*>(dst + 8) = *reinterpret_cast<uint4*>(&outp[8]);
        }
    } else {
        const int idx = (blockIdx.x - 48)*256 + tid;   // 0..131071
        const int t   = idx >> 5;
        const int hp  = idx & 31;
        const float inv = __builtin_exp2f(-(float)hp * (13.287712379549449f / 32.f));
        float sn, cs;
        sincosf((float)t * inv, &sn, &cs);
        *reinterpret_cast<float2*>(&tab[2*idx]) = float2{cs, sn};
    }
}

// ---------------------------------------------------------------------------
// Kernel 1: bf16 MFMA QKV projection + fused table-RoPE. q scaled by
// 0.125*log2(e) -> attention scores land in log2 domain (exp -> exp2).
// ---------------------------------------------------------------------------
__global__ __launch_bounds__(512, 2) void qkv_mfma_kernel(
    const float* __restrict__ x, const unsigned short* __restrict__ wt,
    const float* __restrict__ tab,
    unsigned short* __restrict__ qb, unsigned short* __restrict__ kb,
    unsigned short* __restrict__ vtb)
{
    __shared__ unsigned short SM[32768];     // 64KB: As0|As1 (8K+8K) Ws0|Ws1 (24K+24K)

    const int tid  = threadIdx.x;
    const int w    = tid >> 6;
    const int lane = tid & 63;
    const int rt   = w >> 1;
    const int ch   = w & 1;
    const int lr   = lane & 15;
    const int lg   = lane >> 4;
    const int rb   = blockIdx.x * 64;

    const int ar = tid >> 3;
    const int ac = (tid & 7) * 8;

    float4 axr[2];

    auto load_A = [&](int t) {
        const float* p = &x[(size_t)(rb + ar)*C_ + t*64 + ac];
        axr[0] = *reinterpret_cast<const float4*>(p);
        axr[1] = *reinterpret_cast<const float4*>(p + 4);
    };
    auto write_A = [&](int buf) {
        unsigned tmp[4];
        tmp[0] = pk2bf(axr[0].x, axr[0].y);
        tmp[1] = pk2bf(axr[0].z, axr[0].w);
        tmp[2] = pk2bf(axr[1].x, axr[1].y);
        tmp[3] = pk2bf(axr[1].z, axr[1].w);
        const int off = buf*8192 + ar*128 + ((ac*2) ^ ((ar & 7) << 4));
        *reinterpret_cast<uint4*>((char*)SM + off) = *reinterpret_cast<uint4*>(tmp);
    };
    auto stage_W = [&](int t, int buf) {
        #pragma unroll
        for (int s = 0; s < 3; ++s) {
            const int slot = s*512 + tid;
            const int r    = slot >> 3;
            const int c8   = (slot & 7) * 8;
            const int c8s  = c8 ^ ((r & 7) << 3);
            gld16(&wt[(size_t)r*C_ + t*64 + c8s],
                  (char*)SM + 16384 + buf*24576 + slot*16);
        }
    };

    f32x4 acc[6];
    #pragma unroll
    for (int j = 0; j < 6; ++j) acc[j] = f32x4{0.f, 0.f, 0.f, 0.f};

    load_A(0);
    stage_W(0, 0);
    write_A(0);
    load_A(1);

    for (int t = 0; t < 16; ++t) {
        const int cur = t & 1, nxt = cur ^ 1;
        __syncthreads();
        if (t < 15) { stage_W(t + 1, nxt); write_A(nxt); }
        if (t < 14) load_A(t + 2);
        char* Acur = (char*)SM + cur*8192;
        char* Wcur = (char*)SM + 16384 + cur*24576;
        #pragma unroll
        for (int kh = 0; kh < 2; ++kh) {
            const int arow = rt*16 + lr;
            bf16x8 af = *reinterpret_cast<const bf16x8*>(
                Acur + arow*128 + ((kh*64 + lg*16) ^ ((arow & 7) << 4)));
            #pragma unroll
            for (int j = 0; j < 6; ++j) {
                const int n = ch*96 + j*16 + lr;
                bf16x8 bf = *reinterpret_cast<const bf16x8*>(
                    Wcur + n*128 + ((kh*64 + lg*16) ^ ((n & 7) << 4)));
                acc[j] = __builtin_amdgcn_mfma_f32_16x16x32_bf16(af, bf, acc[j], 0, 0, 0);
            }
        }
    }

    __syncthreads();
    const int rl0  = rt*16 + lg*4;
    const int row0 = rb + rl0;
    #pragma unroll
    for (int j = 0; j < 6; ++j) {
        const int c = ch*96 + j*16 + lr;
        const int m = c >> 6;
        const int h = c & 63;
        if (m < 2) {
            const int base_ls = (m == 0) ? 0 : 4096;
            // q scale: 0.125 (softmax) * log2(e) (exp2 domain)
            const float qs = (m == 0) ? 0.18033688011112042f : 1.0f;
            const int hp = h >> 1;
            #pragma unroll
            for (int i = 0; i < 4; ++i) {
                const float v  = acc[j][i];
                const float pr = __shfl_xor(v, 1);
                if (!(h & 1)) {
                    const int tp = (row0 + i) & (T_ - 1);
                    const float2 cssn = *reinterpret_cast<const float2*>(
                        &tab[((size_t)tp*32 + hp)*2]);
                    const float oe = (v*cssn.x - pr*cssn.y) * qs;
                    const float oo = (v*cssn.y + pr*cssn.x) * qs;
                    *reinterpret_cast<unsigned*>(&SM[base_ls + (rl0 + i)*64 + h]) =
                        pk2bf(oe, oo);
                }
            }
        } else {
            unsigned short pk[4];
            #pragma unroll
            for (int i = 0; i < 4; ++i) pk[i] = f2bf(acc[j][i]);
            char* vbase = (char*)SM + 16384 + h*128;
            *reinterpret_cast<uint2*>(vbase + ((rl0*2) ^ ((h & 7) << 3))) =
                *reinterpret_cast<uint2*>(pk);
        }
    }
    __syncthreads();
    {
        const int row = tid >> 3;
        const int h0  = (tid & 7) * 8;
        *reinterpret_cast<uint4*>(&qb[(size_t)(rb + row)*H_ + h0]) =
            *reinterpret_cast<const uint4*>(&SM[row*64 + h0]);
        *reinterpret_cast<uint4*>(&kb[(size_t)(rb + row)*H_ + h0]) =
            *reinterpret_cast<const uint4*>(&SM[4096 + row*64 + h0]);
        const int h  = tid >> 3;
        const int t0 = (tid & 7) * 8;
        char* vbase = (char*)SM + 16384 + h*128;
        uint2 a  = *reinterpret_cast<uint2*>(vbase + (((t0*2)    ) ^ ((h & 7) << 3)));
        uint2 b2 = *reinterpret_cast<uint2*>(vbase + (((t0*2) + 8) ^ ((h & 7) << 3)));
        const int bh  = (rb >> 12)*64 + h;
        const int tp0 = rb & (T_ - 1);
        uint4 o; o.x = a.x; o.y = a.y; o.z = b2.x; o.w = b2.y;
        *reinterpret_cast<uint4*>(&vtb[(size_t)bh*T_ + tp0 + t0]) = o;
    }
}

// ---------------------------------------------------------------------------
// Kernel 2: BQ=256 split-K flash attention. 512 thr = 8 waves; wave owns
// 32 q-rows (two 16-row subtiles). Block-step count halves vs BQ=128 while
// each step does 2x MFMA against the same barrier+DMA cost. CH=4 k-tiles
// per chunk -> ns = 4 uniformly. LDS 64KB (K/V dbuf 32K + P 32K) ->
// 2 blocks/CU, 16 waves/CU. exp2-domain softmax, unconditional rescale.
// ---------------------------------------------------------------------------
__global__ __launch_bounds__(512, 4) void attn_chunk_kernel(
    const unsigned short* __restrict__ qb, const unsigned short* __restrict__ kb,
    const unsigned short* __restrict__ vtb,
    unsigned short* __restrict__ partO, float* __restrict__ partML,
    int CH, int per_batch)
{
    // LDS bytes: K dbuf [0,16K), V dbuf [16K,32K), P per-wave 4KB [32K,64K)
    __shared__ unsigned short SM[32768];     // 64KB

    const int tid  = threadIdx.x;
    const int w    = tid >> 6;       // wave 0..7, owns q-rows w*32..w*32+31
    const int lane = tid & 63;
    const int lr   = lane & 15;
    const int lg   = lane >> 4;

    const int cid = blockIdx.x;
    const int b   = cid / per_batch;
    int rem = cid - b*per_batch;
    int qt = 0, c = 0;
    for (qt = 0; qt < 16; ++qt) {
        const int n = (4*qt + 4 + CH - 1) / CH;
        if (rem < n) { c = rem; break; }
        rem -= n;
    }

    const int q0  = qt * 256;
    const int kt0 = c * CH;
    const int ntk = 4*qt + 4;
    const int ns  = min(kt0 + CH, ntk) - kt0;
    const size_t rbase = (size_t)b * T_;
    const int dtile = 4*qt + (w >> 1);   // wave-uniform diagonal k-tile

    char* Pw = (char*)SM + 32768 + w*4096;

    bf16x8 qf[2][2];
    #pragma unroll
    for (int s16 = 0; s16 < 2; ++s16) {
        const unsigned short* qp = qb + (rbase + q0 + w*32 + s16*16 + lr)*H_ + lg*8;
        qf[s16][0] = *reinterpret_cast<const bf16x8*>(qp);
        qf[s16][1] = *reinterpret_cast<const bf16x8*>(qp + 32);
    }

    float mrow[2] = {-1e30f, -1e30f};
    float lrow[2] = {0.f, 0.f};
    f32x4 acc[2][4];
    #pragma unroll
    for (int s16 = 0; s16 < 2; ++s16)
        #pragma unroll
        for (int hs = 0; hs < 4; ++hs) acc[s16][hs] = f32x4{0.f, 0.f, 0.f, 0.f};

    const int srow = tid >> 3;           // 0..63
    const int scol = (tid & 7) * 8;      // elem col
    auto stage_dma = [&](int kt, int buf) {
        const int c8s = scol ^ ((srow & 7) << 3);
        gld16(&kb[(rbase + (size_t)kt*64 + srow)*H_ + c8s],
              (char*)SM + buf*8192 + tid*16);
        gld16(&vtb[((size_t)(b*64 + srow))*T_ + (size_t)kt*64 + c8s],
              (char*)SM + 16384 + buf*8192 + tid*16);
    };

    stage_dma(kt0, 0);

    for (int s = 0; s < ns; ++s) {
        __syncthreads();                 // buf s&1 DMA drained + prior reads done
        if (s + 1 < ns) stage_dma(kt0 + s + 1, (s + 1) & 1);
        const int kt = kt0 + s;
        char* Kb = (char*)SM + (s & 1)*8192;
        char* Vb = (char*)SM + 16384 + (s & 1)*8192;

        if (kt <= dtile) {               // wave-uniform causal skip
            // ---- S^T = K Q^T for both subtiles (K frags shared) ----
            f32x4 st[2][4];
            __builtin_amdgcn_s_setprio(1);
            #pragma unroll
            for (int ks = 0; ks < 4; ++ks) {
                const int rr2 = ks*16 + lr;
                const int sw  = (rr2 & 7) << 4;
                bf16x8 kf0 = *reinterpret_cast<const bf16x8*>(Kb + rr2*128 + ((lg*16     ) ^ sw));
                bf16x8 kf1 = *reinterpret_cast<const bf16x8*>(Kb + rr2*128 + ((lg*16 + 64) ^ sw));
                #pragma unroll
                for (int s16 = 0; s16 < 2; ++s16) {
                    f32x4 t = {0.f, 0.f, 0.f, 0.f};
                    t = __builtin_amdgcn_mfma_f32_16x16x32_bf16(kf0, qf[s16][0], t, 0, 0, 0);
                    t = __builtin_amdgcn_mfma_f32_16x16x32_bf16(kf1, qf[s16][1], t, 0, 0, 0);
                    st[s16][ks] = t;
                }
            }
            __builtin_amdgcn_s_setprio(0);

            // ---- exp2-domain online softmax, two independent chains ----
            float scl[2];
            const int swp = (lr & 7) << 4;
            #pragma unroll
            for (int s16 = 0; s16 < 2; ++s16) {
                const int qg = q0 + w*32 + s16*16 + lr;
                float mx = -1e30f;
                if (kt == dtile) {
                    #pragma unroll
                    for (int ks = 0; ks < 4; ++ks)
                        #pragma unroll
                        for (int i = 0; i < 4; ++i) {
                            const int kg = kt*64 + ks*16 + lg*4 + i;
                            const float v = (kg <= qg) ? st[s16][ks][i] : -1e30f;
                            st[s16][ks][i] = v;
                            mx = fmaxf(mx, v);
                        }
                } else {
                    #pragma unroll
                    for (int ks = 0; ks < 4; ++ks)
                        #pragma unroll
                        for (int i = 0; i < 4; ++i) mx = fmaxf(mx, st[s16][ks][i]);
                }
                mx = fmaxf(mx, __shfl_xor(mx, 16));
                mx = fmaxf(mx, __shfl_xor(mx, 32));
                const float mn = fmaxf(mrow[s16], mx);
                scl[s16] = __builtin_exp2f(mrow[s16] - mn);
                float ls = 0.f;
                #pragma unroll
                for (int ks = 0; ks < 4; ++ks)
                    #pragma unroll
                    for (int i = 0; i < 4; ++i) {
                        const float p = __builtin_exp2f(st[s16][ks][i] - mn);
                        st[s16][ks][i] = p;
                        ls += p;
                    }
                ls += __shfl_xor(ls, 16);
                ls += __shfl_xor(ls, 32);
                lrow[s16] = lrow[s16]*scl[s16] + ls;
                mrow[s16] = mn;

                // P -> bf16 -> per-wave LDS (rows s16*16 + lr)
                const int pr = s16*16 + lr;
                #pragma unroll
                for (int ks = 0; ks < 4; ++ks) {
                    const unsigned u0 = pk2bf(st[s16][ks][0], st[s16][ks][1]);
                    const unsigned u1 = pk2bf(st[s16][ks][2], st[s16][ks][3]);
                    *reinterpret_cast<uint2*>(Pw + pr*128 + ((ks*32 + lg*8) ^ swp)) =
                        make_uint2(u0, u1);
                }
            }

            // ---- rescale O ----
            #pragma unroll
            for (int s16 = 0; s16 < 2; ++s16) {
                float sclr[4];
                #pragma unroll
                for (int i = 0; i < 4; ++i) sclr[i] = __shfl(scl[s16], lg*4 + i);
                #pragma unroll
                for (int hs = 0; hs < 4; ++hs)
                    #pragma unroll
                    for (int i = 0; i < 4; ++i) acc[s16][hs][i] *= sclr[i];
            }

            // ---- O += P V (V frags shared across subtiles) ----
            bf16x8 pf[2][2];
            #pragma unroll
            for (int s16 = 0; s16 < 2; ++s16) {
                const int pr = s16*16 + lr;
                pf[s16][0] = *reinterpret_cast<const bf16x8*>(Pw + pr*128 + ((lg*16     ) ^ swp));
                pf[s16][1] = *reinterpret_cast<const bf16x8*>(Pw + pr*128 + ((lg*16 + 64) ^ swp));
            }
            __builtin_amdgcn_s_setprio(1);
            #pragma unroll
            for (int hs = 0; hs < 4; ++hs) {
                const int rv  = hs*16 + lr;
                const int swv = (rv & 7) << 4;
                bf16x8 vf0 = *reinterpret_cast<const bf16x8*>(Vb + rv*128 + ((lg*16     ) ^ swv));
                bf16x8 vf1 = *reinterpret_cast<const bf16x8*>(Vb + rv*128 + ((lg*16 + 64) ^ swv));
                #pragma unroll
                for (int s16 = 0; s16 < 2; ++s16) {
                    acc[s16][hs] = __builtin_amdgcn_mfma_f32_16x16x32_bf16(pf[s16][0], vf0, acc[s16][hs], 0, 0, 0);
                    acc[s16][hs] = __builtin_amdgcn_mfma_f32_16x16x32_bf16(pf[s16][1], vf1, acc[s16][hs], 0, 0, 0);
                }
            }
            __builtin_amdgcn_s_setprio(0);
        }
    }

    // ---- write partial: m,l fp32; O staged in LDS then coalesced ----
    #pragma unroll
    for (int s16 = 0; s16 < 2; ++s16) {
        const int myrow = w*32 + s16*16 + lr;
        if (lg == 0) {
            partML[(size_t)cid*512 + myrow]       = mrow[s16];
            partML[(size_t)cid*512 + 256 + myrow] = lrow[s16];
        }
    }
    __syncthreads();                          // all LDS use done, reuse K/V region
    unsigned short* Ols = &SM[0];             // 32KB: [256 rows][64 h]
    #pragma unroll
    for (int s16 = 0; s16 < 2; ++s16)
        #pragma unroll
        for (int hs = 0; hs < 4; ++hs)
            #pragma unroll
            for (int i = 0; i < 4; ++i)
                Ols[(w*32 + s16*16 + lg*4 + i)*64 + hs*16 + lr] =
                    f2bf(acc[s16][hs][i]);
    __syncthreads();
    {
        const int e0 = tid * 32;              // 16384 elems / 512 thr
        #pragma unroll
        for (int j = 0; j < 4; ++j)
            *reinterpret_cast<uint4*>(&partO[(size_t)cid*16384 + e0 + 8*j]) =
                *reinterpret_cast<const uint4*>(&Ols[e0 + 8*j]);
    }
}

// ---------------------------------------------------------------------------
// Kernel 3: combine partials per (b, 256-row q-tile, quarter). 256 blocks.
// Weights are 2^(mi - M) (log2-domain m). nc <= 16.
// ---------------------------------------------------------------------------
__global__ __launch_bounds__(256) void combine_kernel(
    const unsigned short* __restrict__ partO, const float* __restrict__ partML,
    float* __restrict__ out, int CH, int per_batch)
{
    const int bq   = blockIdx.x;          // b(2b) | qt(4b) | quarter(2b)
    const int b    = bq >> 6;
    const int rest = bq & 63;
    const int qt   = rest >> 2;
    const int qtr  = rest & 3;

    int pre = 0;
    for (int j = 0; j < qt; ++j) pre += (4*j + 4 + CH - 1) / CH;
    const int nc = (4*qt + 4 + CH - 1) / CH;
    const int cb = b*per_batch + pre;

    const int tid = threadIdx.x;
    const int row = qtr*64 + (tid >> 2);  // 0..255 within tile
    const int h0  = (tid & 3) * 16;

    float mi[16], wi[16];
    float M = -1e30f;
    #pragma unroll
    for (int i = 0; i < 16; ++i) if (i < nc) {
        mi[i] = partML[(size_t)(cb + i)*512 + row];
        M = fmaxf(M, mi[i]);
    }
    float L = 0.f;
    #pragma unroll
    for (int i = 0; i < 16; ++i) if (i < nc) {
        wi[i] = __builtin_exp2f(mi[i] - M);
        L += partML[(size_t)(cb + i)*512 + 256 + row] * wi[i];
    }
    const float inv = 1.f / L;

    float o[16];
    #pragma unroll
    for (int j = 0; j < 16; ++j) o[j] = 0.f;
    #pragma unroll
    for (int i = 0; i < 16; ++i) if (i < nc) {
        const unsigned short* p = &partO[(size_t)(cb + i)*16384 + (size_t)row*64 + h0];
        uint4 u0 = *reinterpret_cast<const uint4*>(p);
        uint4 u1 = *reinterpret_cast<const uint4*>(p + 8);
        const unsigned* uu = (const unsigned*)&u0;
        #pragma unroll
        for (int j = 0; j < 4; ++j) {
            o[2*j]   += bf2f((unsigned short)(uu[j] & 0xffffu)) * wi[i];
            o[2*j+1] += bf2f((unsigned short)(uu[j] >> 16))     * wi[i];
        }
        const unsigned* uv = (const unsigned*)&u1;
        #pragma unroll
        for (int j = 0; j < 4; ++j) {
            o[8+2*j]   += bf2f((unsigned short)(uv[j] & 0xffffu)) * wi[i];
            o[8+2*j+1] += bf2f((unsigned short)(uv[j] >> 16))     * wi[i];
        }
    }
    float* op = &out[((size_t)b*T_ + (size_t)qt*256 + row)*H_ + h0];
    #pragma unroll
    for (int j = 0; j < 4; ++j) {
        float4 v = make_float4(o[4*j]*inv, o[4*j+1]*inv, o[4*j+2]*inv, o[4*j+3]*inv);
        *reinterpret_cast<float4*>(op + 4*j) = v;
    }
}

// ---------------------------------------------------------------------------
extern "C" void kernel_launch(void* const* d_in, const int* in_sizes, int n_in,
                              void* d_out, int out_size, void* d_ws, size_t ws_size,
                              hipStream_t stream) {
    const float* x  = (const float*)d_in[0];
    const float* wq = (const float*)d_in[1];
    const float* wk = (const float*)d_in[2];
    const float* wv = (const float*)d_in[3];
    float* out = (float*)d_out;

    unsigned short* qb  = (unsigned short*)d_ws;                   // 2MB
    unsigned short* kb  = qb  + (size_t)ROWS_ * H_;                // 2MB
    unsigned short* vtb = kb  + (size_t)ROWS_ * H_;                // 2MB
    unsigned short* wt  = vtb + (size_t)ROWS_ * H_;                // 384KB

    // chunk size CH (k-tiles per chunk): prefer 4 (544 blocks) if ws allows.
    const size_t fixed = (size_t)3*ROWS_*H_*2 + (size_t)3*64*C_*2;
    auto pb = [](int CH) { int s = 0;
        for (int qt = 0; qt < 16; ++qt) s += (4*qt + 4 + CH - 1)/CH; return s; };
    int CH = 4, per_batch = pb(4);
    if (ws_size < fixed + (size_t)4*per_batch*(16384*2 + 512*4)) {
        CH = 8; per_batch = pb(8);
    }
    const int nblk = 4 * per_batch;

    unsigned short* partO  = wt + (size_t)3*64*C_;
    float*          partML = (float*)(partO + (size_t)nblk*16384);

    // RoPE table (1MB) aliased onto partO: written before qkv, consumed by
    // qkv, then overwritten by attn_chunk. Stream-ordered => deterministic.
    float* rope_tab = (float*)partO;

    prep_kernel<<<560, 256, 0, stream>>>(wq, wk, wv, wt, rope_tab);
    qkv_mfma_kernel<<<ROWS_/64, 512, 0, stream>>>(x, wt, rope_tab, qb, kb, vtb);
    attn_chunk_kernel<<<nblk, 512, 0, stream>>>(qb, kb, vtb, partO, partML,
                                                CH, per_batch);
    combine_kernel<<<256, 256, 0, stream>>>(partO, partML, out, CH, per_batch);
}

// Round 16
// 83.314 us; speedup vs baseline: 1.0252x; 1.0252x over previous
//
#include <hip/hip_runtime.h>
#include <hip/hip_bf16.h>
#include <math.h>

#define B_ 4
#define T_ 4096
#define C_ 1024
#define H_ 64
#define ROWS_ (B_*T_)

typedef __attribute__((ext_vector_type(8))) short bf16x8;
typedef __attribute__((ext_vector_type(4))) float f32x4;

__device__ __forceinline__ unsigned short f2bf(float f) {
    union { float f; unsigned u; } x; x.f = f;
    unsigned r = x.u + 0x7fffu + ((x.u >> 16) & 1u);   // RNE
    return (unsigned short)(r >> 16);
}
__device__ __forceinline__ float bf2f(unsigned short s) {
    union { unsigned u; float f; } x; x.u = ((unsigned)s) << 16;
    return x.f;
}
__device__ __forceinline__ unsigned pk2bf(float a, float b) {
    __hip_bfloat162 h = __float22bfloat162_rn(float2{a, b});
    return *reinterpret_cast<unsigned*>(&h);
}
// async global->LDS DMA, 16B/lane.
__device__ __forceinline__ void gld16(const void* g, void* l) {
    __builtin_amdgcn_global_load_lds(
        (const __attribute__((address_space(1))) unsigned*)g,
        (__attribute__((address_space(3))) unsigned*)l, 16, 0, 0);
}

// ---------------------------------------------------------------------------
// Kernel 0: fused weight prep (blocks 0..47) + RoPE table (blocks 48..559).
// ---------------------------------------------------------------------------
__global__ __launch_bounds__(256) void prep_kernel(
    const float* __restrict__ wq, const float* __restrict__ wk,
    const float* __restrict__ wv, unsigned short* __restrict__ wt,
    float* __restrict__ tab)
{
    __shared__ float ts[64][68];
    const int tid = threadIdx.x;
    if (blockIdx.x < 48) {
        const int m  = blockIdx.x >> 4;
        const int k0 = (blockIdx.x & 15) * 64;
        const float* w = (m == 0) ? wq : (m == 1) ? wk : wv;
        {
            const int r = tid >> 2;
            const int c = (tid & 3) * 16;
            #pragma unroll
            for (int i = 0; i < 4; ++i)
                *reinterpret_cast<float4*>(&ts[r][c + 4*i]) =
                    *reinterpret_cast<const float4*>(&w[(size_t)(k0 + r)*H_ + c + 4*i]);
        }
        __syncthreads();
        {
            const int n  = tid >> 2;
            const int kc = (tid & 3) * 16;
            unsigned short outp[16];
            #pragma unroll
            for (int j = 0; j < 16; ++j) outp[j] = f2bf(ts[kc + j][n]);
            unsigned short* dst = &wt[((size_t)m*64 + n)*C_ + k0 + kc];
            *reinterpret_cast<uint4*>(dst)     = *reinterpret_cast<uint4*>(&outp[0]);
            *reinterpret_cast<uint4*>(dst + 8) = *reinterpret_cast<uint4*>(&outp[8]);
        }
    } else {
        const int idx = (blockIdx.x - 48)*256 + tid;   // 0..131071
        const int t   = idx >> 5;
        const int hp  = idx & 31;
        const float inv = __builtin_exp2f(-(float)hp * (13.287712379549449f / 32.f));
        float sn, cs;
        sincosf((float)t * inv, &sn, &cs);
        *reinterpret_cast<float2*>(&tab[2*idx]) = float2{cs, sn};
    }
}

// ---------------------------------------------------------------------------
// Kernel 1: bf16 MFMA QKV projection + fused table-RoPE. Single barrier per
// K-step: W staged via global_load_lds DMA double-buffered; x reg-staged
// 2 steps ahead into double-buffered As. q scaled by 0.125.
// ---------------------------------------------------------------------------
__global__ __launch_bounds__(512, 2) void qkv_mfma_kernel(
    const float* __restrict__ x, const unsigned short* __restrict__ wt,
    const float* __restrict__ tab,
    unsigned short* __restrict__ qb, unsigned short* __restrict__ kb,
    unsigned short* __restrict__ vtb)
{
    __shared__ unsigned short SM[32768];     // 64KB: As0|As1 (8K+8K) Ws0|Ws1 (24K+24K)

    const int tid  = threadIdx.x;
    const int w    = tid >> 6;
    const int lane = tid & 63;
    const int rt   = w >> 1;
    const int ch   = w & 1;
    const int lr   = lane & 15;
    const int lg   = lane >> 4;
    const int rb   = blockIdx.x * 64;

    const int ar = tid >> 3;
    const int ac = (tid & 7) * 8;

    float4 axr[2];

    auto load_A = [&](int t) {
        const float* p = &x[(size_t)(rb + ar)*C_ + t*64 + ac];
        axr[0] = *reinterpret_cast<const float4*>(p);
        axr[1] = *reinterpret_cast<const float4*>(p + 4);
    };
    auto write_A = [&](int buf) {
        unsigned tmp[4];
        tmp[0] = pk2bf(axr[0].x, axr[0].y);
        tmp[1] = pk2bf(axr[0].z, axr[0].w);
        tmp[2] = pk2bf(axr[1].x, axr[1].y);
        tmp[3] = pk2bf(axr[1].z, axr[1].w);
        const int off = buf*8192 + ar*128 + ((ac*2) ^ ((ar & 7) << 4));
        *reinterpret_cast<uint4*>((char*)SM + off) = *reinterpret_cast<uint4*>(tmp);
    };
    auto stage_W = [&](int t, int buf) {
        #pragma unroll
        for (int s = 0; s < 3; ++s) {
            const int slot = s*512 + tid;
            const int r    = slot >> 3;
            const int c8   = (slot & 7) * 8;
            const int c8s  = c8 ^ ((r & 7) << 3);
            gld16(&wt[(size_t)r*C_ + t*64 + c8s],
                  (char*)SM + 16384 + buf*24576 + slot*16);
        }
    };

    f32x4 acc[6];
    #pragma unroll
    for (int j = 0; j < 6; ++j) acc[j] = f32x4{0.f, 0.f, 0.f, 0.f};

    load_A(0);
    stage_W(0, 0);
    write_A(0);
    load_A(1);

    for (int t = 0; t < 16; ++t) {
        const int cur = t & 1, nxt = cur ^ 1;
        __syncthreads();
        if (t < 15) { stage_W(t + 1, nxt); write_A(nxt); }
        if (t < 14) load_A(t + 2);
        char* Acur = (char*)SM + cur*8192;
        char* Wcur = (char*)SM + 16384 + cur*24576;
        #pragma unroll
        for (int kh = 0; kh < 2; ++kh) {
            const int arow = rt*16 + lr;
            bf16x8 af = *reinterpret_cast<const bf16x8*>(
                Acur + arow*128 + ((kh*64 + lg*16) ^ ((arow & 7) << 4)));
            #pragma unroll
            for (int j = 0; j < 6; ++j) {
                const int n = ch*96 + j*16 + lr;
                bf16x8 bf = *reinterpret_cast<const bf16x8*>(
                    Wcur + n*128 + ((kh*64 + lg*16) ^ ((n & 7) << 4)));
                acc[j] = __builtin_amdgcn_mfma_f32_16x16x32_bf16(af, bf, acc[j], 0, 0, 0);
            }
        }
    }

    __syncthreads();
    const int rl0  = rt*16 + lg*4;
    const int row0 = rb + rl0;
    #pragma unroll
    for (int j = 0; j < 6; ++j) {
        const int c = ch*96 + j*16 + lr;
        const int m = c >> 6;
        const int h = c & 63;
        if (m < 2) {
            const int base_ls = (m == 0) ? 0 : 4096;
            const float qs = (m == 0) ? 0.125f : 1.0f;
            const int hp = h >> 1;
            #pragma unroll
            for (int i = 0; i < 4; ++i) {
                const float v  = acc[j][i];
                const float pr = __shfl_xor(v, 1);
                if (!(h & 1)) {
                    const int tp = (row0 + i) & (T_ - 1);
                    const float2 cssn = *reinterpret_cast<const float2*>(
                        &tab[((size_t)tp*32 + hp)*2]);
                    const float oe = (v*cssn.x - pr*cssn.y) * qs;
                    const float oo = (v*cssn.y + pr*cssn.x) * qs;
                    *reinterpret_cast<unsigned*>(&SM[base_ls + (rl0 + i)*64 + h]) =
                        pk2bf(oe, oo);
                }
            }
        } else {
            unsigned short pk[4];
            #pragma unroll
            for (int i = 0; i < 4; ++i) pk[i] = f2bf(acc[j][i]);
            char* vbase = (char*)SM + 16384 + h*128;
            *reinterpret_cast<uint2*>(vbase + ((rl0*2) ^ ((h & 7) << 3))) =
                *reinterpret_cast<uint2*>(pk);
        }
    }
    __syncthreads();
    {
        const int row = tid >> 3;
        const int h0  = (tid & 7) * 8;
        *reinterpret_cast<uint4*>(&qb[(size_t)(rb + row)*H_ + h0]) =
            *reinterpret_cast<const uint4*>(&SM[row*64 + h0]);
        *reinterpret_cast<uint4*>(&kb[(size_t)(rb + row)*H_ + h0]) =
            *reinterpret_cast<const uint4*>(&SM[4096 + row*64 + h0]);
        const int h  = tid >> 3;
        const int t0 = (tid & 7) * 8;
        char* vbase = (char*)SM + 16384 + h*128;
        uint2 a  = *reinterpret_cast<uint2*>(vbase + (((t0*2)    ) ^ ((h & 7) << 3)));
        uint2 b2 = *reinterpret_cast<uint2*>(vbase + (((t0*2) + 8) ^ ((h & 7) << 3)));
        const int bh  = (rb >> 12)*64 + h;
        const int tp0 = rb & (T_ - 1);
        uint4 o; o.x = a.x; o.y = a.y; o.z = b2.x; o.w = b2.y;
        *reinterpret_cast<uint4*>(&vtb[(size_t)bh*T_ + tp0 + t0]) = o;
    }
}

// ---------------------------------------------------------------------------
// Kernel 2: BQ=128 split-K flash attention (round-13 structure, best known).
// Wave owns TWO 16-row q-subtiles; K/V frags shared across subtiles; waves
// above the diagonal skip steps. DMA double-buffered K/V. LDS 40KB ->
// 4 blocks/CU (launch_bounds(256,4) requests it).
// ---------------------------------------------------------------------------
__global__ __launch_bounds__(256, 4) void attn_chunk_kernel(
    const unsigned short* __restrict__ qb, const unsigned short* __restrict__ kb,
    const unsigned short* __restrict__ vtb,
    unsigned short* __restrict__ partO, float* __restrict__ partML,
    int CH, int per_batch)
{
    __shared__ unsigned short Kls[2][4096];
    __shared__ unsigned short Vls[2][4096];
    __shared__ unsigned short Pls[4][2048];

    const int tid  = threadIdx.x;
    const int w    = tid >> 6;       // wave 0..3, owns q-rows w*32..w*32+31
    const int lane = tid & 63;
    const int lr   = lane & 15;
    const int lg   = lane >> 4;

    const int cid = blockIdx.x;
    const int b   = cid / per_batch;
    int r0 = cid - b*per_batch;
    const int G = CH >> 1;
    int a = 0, off = 0;
    while (r0 >= off + G*(a + 1)) { off += G*(a + 1); ++a; }
    const int idx = r0 - off;
    const int qt  = G*a + idx/(a + 1);   // 128-row q-tile, 0..31
    const int c   = idx % (a + 1);

    const int q0  = qt * 128;
    const int kt0 = c * CH;
    const int ntk = 2*qt + 2;
    const int ns  = min(kt0 + CH, ntk) - kt0;
    const size_t rbase = (size_t)b * T_;
    const int dtile = 2*qt + (w >> 1);   // wave-uniform diagonal k-tile

    char* Pw = (char*)&Pls[w][0];

    bf16x8 qf[2][2];
    #pragma unroll
    for (int s16 = 0; s16 < 2; ++s16) {
        const unsigned short* qp = qb + (rbase + q0 + w*32 + s16*16 + lr)*H_ + lg*8;
        qf[s16][0] = *reinterpret_cast<const bf16x8*>(qp);
        qf[s16][1] = *reinterpret_cast<const bf16x8*>(qp + 32);
    }

    float mrow[2] = {-1e30f, -1e30f};
    float lrow[2] = {0.f, 0.f};
    f32x4 acc[2][4];
    #pragma unroll
    for (int s16 = 0; s16 < 2; ++s16)
        #pragma unroll
        for (int hs = 0; hs < 4; ++hs) acc[s16][hs] = f32x4{0.f, 0.f, 0.f, 0.f};

    const int srow = tid >> 3;           // 0..31
    const int scol = (tid & 7) * 8;      // elem col
    auto stage_dma = [&](int kt, int buf) {
        #pragma unroll
        for (int s = 0; s < 2; ++s) {
            const int r    = s*32 + srow;
            const int c8s  = scol ^ ((r & 7) << 3);
            const int slot = s*256 + tid;
            gld16(&kb[(rbase + (size_t)kt*64 + r)*H_ + c8s],
                  (char*)&Kls[buf][0] + slot*16);
            gld16(&vtb[((size_t)(b*64 + r))*T_ + (size_t)kt*64 + c8s],
                  (char*)&Vls[buf][0] + slot*16);
        }
    };

    stage_dma(kt0, 0);

    for (int s = 0; s < ns; ++s) {
        __syncthreads();                 // buf s&1 DMA drained + prior reads done
        if (s + 1 < ns) stage_dma(kt0 + s + 1, (s + 1) & 1);
        const int kt = kt0 + s;
        char* Kb = (char*)&Kls[s & 1][0];
        char* Vb = (char*)&Vls[s & 1][0];

        if (kt <= dtile) {               // wave-uniform causal skip
            // ---- S^T = K Q^T for both subtiles (K frags shared) ----
            f32x4 st[2][4];
            __builtin_amdgcn_s_setprio(1);
            #pragma unroll
            for (int ks = 0; ks < 4; ++ks) {
                const int rr2 = ks*16 + lr;
                const int sw  = (rr2 & 7) << 4;
                bf16x8 kf0 = *reinterpret_cast<const bf16x8*>(Kb + rr2*128 + ((lg*16     ) ^ sw));
                bf16x8 kf1 = *reinterpret_cast<const bf16x8*>(Kb + rr2*128 + ((lg*16 + 64) ^ sw));
                #pragma unroll
                for (int s16 = 0; s16 < 2; ++s16) {
                    f32x4 t = {0.f, 0.f, 0.f, 0.f};
                    t = __builtin_amdgcn_mfma_f32_16x16x32_bf16(kf0, qf[s16][0], t, 0, 0, 0);
                    t = __builtin_amdgcn_mfma_f32_16x16x32_bf16(kf1, qf[s16][1], t, 0, 0, 0);
                    st[s16][ks] = t;
                }
            }
            __builtin_amdgcn_s_setprio(0);

            // ---- online softmax, two independent chains ----
            float scl[2];
            const int swp = (lr & 7) << 4;
            #pragma unroll
            for (int s16 = 0; s16 < 2; ++s16) {
                const int qg = q0 + w*32 + s16*16 + lr;
                float mx = -1e30f;
                if (kt == dtile) {
                    #pragma unroll
                    for (int ks = 0; ks < 4; ++ks)
                        #pragma unroll
                        for (int i = 0; i < 4; ++i) {
                            const int kg = kt*64 + ks*16 + lg*4 + i;
                            const float v = (kg <= qg) ? st[s16][ks][i] : -1e30f;
                            st[s16][ks][i] = v;
                            mx = fmaxf(mx, v);
                        }
                } else {
                    #pragma unroll
                    for (int ks = 0; ks < 4; ++ks)
                        #pragma unroll
                        for (int i = 0; i < 4; ++i) mx = fmaxf(mx, st[s16][ks][i]);
                }
                mx = fmaxf(mx, __shfl_xor(mx, 16));
                mx = fmaxf(mx, __shfl_xor(mx, 32));
                const float mn = fmaxf(mrow[s16], mx);
                scl[s16] = __expf(mrow[s16] - mn);
                float ls = 0.f;
                #pragma unroll
                for (int ks = 0; ks < 4; ++ks)
                    #pragma unroll
                    for (int i = 0; i < 4; ++i) {
                        const float p = __expf(st[s16][ks][i] - mn);
                        st[s16][ks][i] = p;
                        ls += p;
                    }
                ls += __shfl_xor(ls, 16);
                ls += __shfl_xor(ls, 32);
                lrow[s16] = lrow[s16]*scl[s16] + ls;
                mrow[s16] = mn;

                // P -> bf16 -> per-wave LDS (rows s16*16 + lr)
                const int pr = s16*16 + lr;
                #pragma unroll
                for (int ks = 0; ks < 4; ++ks) {
                    const unsigned u0 = pk2bf(st[s16][ks][0], st[s16][ks][1]);
                    const unsigned u1 = pk2bf(st[s16][ks][2], st[s16][ks][3]);
                    *reinterpret_cast<uint2*>(Pw + pr*128 + ((ks*32 + lg*8) ^ swp)) =
                        make_uint2(u0, u1);
                }
            }

            // ---- rescale O ----
            #pragma unroll
            for (int s16 = 0; s16 < 2; ++s16) {
                float sclr[4];
                #pragma unroll
                for (int i = 0; i < 4; ++i) sclr[i] = __shfl(scl[s16], lg*4 + i);
                #pragma unroll
                for (int hs = 0; hs < 4; ++hs)
                    #pragma unroll
                    for (int i = 0; i < 4; ++i) acc[s16][hs][i] *= sclr[i];
            }

            // ---- O += P V (V frags shared across subtiles) ----
            bf16x8 pf[2][2];
            #pragma unroll
            for (int s16 = 0; s16 < 2; ++s16) {
                const int pr = s16*16 + lr;
                pf[s16][0] = *reinterpret_cast<const bf16x8*>(Pw + pr*128 + ((lg*16     ) ^ swp));
                pf[s16][1] = *reinterpret_cast<const bf16x8*>(Pw + pr*128 + ((lg*16 + 64) ^ swp));
            }
            __builtin_amdgcn_s_setprio(1);
            #pragma unroll
            for (int hs = 0; hs < 4; ++hs) {
                const int rv  = hs*16 + lr;
                const int swv = (rv & 7) << 4;
                bf16x8 vf0 = *reinterpret_cast<const bf16x8*>(Vb + rv*128 + ((lg*16     ) ^ swv));
                bf16x8 vf1 = *reinterpret_cast<const bf16x8*>(Vb + rv*128 + ((lg*16 + 64) ^ swv));
                #pragma unroll
                for (int s16 = 0; s16 < 2; ++s16) {
                    acc[s16][hs] = __builtin_amdgcn_mfma_f32_16x16x32_bf16(pf[s16][0], vf0, acc[s16][hs], 0, 0, 0);
                    acc[s16][hs] = __builtin_amdgcn_mfma_f32_16x16x32_bf16(pf[s16][1], vf1, acc[s16][hs], 0, 0, 0);
                }
            }
            __builtin_amdgcn_s_setprio(0);
        }
    }

    // ---- write partial: m,l fp32; O staged in LDS then coalesced ----
    #pragma unroll
    for (int s16 = 0; s16 < 2; ++s16) {
        const int myrow = w*32 + s16*16 + lr;
        if (lg == 0) {
            partML[(size_t)cid*256 + myrow]       = mrow[s16];
            partML[(size_t)cid*256 + 128 + myrow] = lrow[s16];
        }
    }
    __syncthreads();                          // all LDS use done, reuse Kls
    unsigned short* Ols = &Kls[0][0];         // 16KB: [128 rows][64 h]
    #pragma unroll
    for (int s16 = 0; s16 < 2; ++s16)
        #pragma unroll
        for (int hs = 0; hs < 4; ++hs)
            #pragma unroll
            for (int i = 0; i < 4; ++i)
                Ols[(w*32 + s16*16 + lg*4 + i)*64 + hs*16 + lr] =
                    f2bf(acc[s16][hs][i]);
    __syncthreads();
    {
        const int e0 = tid * 32;              // 8192 elems / 256 thr
        #pragma unroll
        for (int j = 0; j < 4; ++j)
            *reinterpret_cast<uint4*>(&partO[(size_t)cid*8192 + e0 + 8*j]) =
                *reinterpret_cast<const uint4*>(&Ols[e0 + 8*j]);
    }
}

// ---------------------------------------------------------------------------
// Kernel 3: combine partials per (b, 128-row q-tile, half). 256 blocks.
// ---------------------------------------------------------------------------
__global__ __launch_bounds__(256) void combine_kernel(
    const unsigned short* __restrict__ partO, const float* __restrict__ partML,
    float* __restrict__ out, int CH, int per_batch)
{
    const int bq   = blockIdx.x;          // b(2b) | qt(5b) | half(1b)
    const int b    = bq >> 6;
    const int qt   = (bq >> 1) & 31;
    const int half = bq & 1;
    const int G  = CH >> 1;
    const int a  = qt / G;
    const int nc = a + 1;                 // <= 8
    const int cb = b*per_batch + (G*a*(a + 1))/2 + (qt - G*a)*(a + 1);

    const int tid = threadIdx.x;
    const int row = half*64 + (tid >> 2); // 0..127 within tile
    const int h0  = (tid & 3) * 16;

    float mi[8], wi[8];
    float M = -1e30f;
    #pragma unroll
    for (int i = 0; i < 8; ++i) if (i < nc) {
        mi[i] = partML[(size_t)(cb + i)*256 + row];
        M = fmaxf(M, mi[i]);
    }
    float L = 0.f;
    #pragma unroll
    for (int i = 0; i < 8; ++i) if (i < nc) {
        wi[i] = __expf(mi[i] - M);
        L += partML[(size_t)(cb + i)*256 + 128 + row] * wi[i];
    }
    const float inv = 1.f / L;

    float o[16];
    #pragma unroll
    for (int j = 0; j < 16; ++j) o[j] = 0.f;
    #pragma unroll
    for (int i = 0; i < 8; ++i) if (i < nc) {
        const unsigned short* p = &partO[(size_t)(cb + i)*8192 + (size_t)row*64 + h0];
        uint4 u0 = *reinterpret_cast<const uint4*>(p);
        uint4 u1 = *reinterpret_cast<const uint4*>(p + 8);
        const unsigned* uu = (const unsigned*)&u0;
        #pragma unroll
        for (int j = 0; j < 4; ++j) {
            o[2*j]   += bf2f((unsigned short)(uu[j] & 0xffffu)) * wi[i];
            o[2*j+1] += bf2f((unsigned short)(uu[j] >> 16))     * wi[i];
        }
        const unsigned* uv = (const unsigned*)&u1;
        #pragma unroll
        for (int j = 0; j < 4; ++j) {
            o[8+2*j]   += bf2f((unsigned short)(uv[j] & 0xffffu)) * wi[i];
            o[8+2*j+1] += bf2f((unsigned short)(uv[j] >> 16))     * wi[i];
        }
    }
    float* op = &out[((size_t)b*T_ + (size_t)qt*128 + row)*H_ + h0];
    #pragma unroll
    for (int j = 0; j < 4; ++j) {
        float4 v = make_float4(o[4*j]*inv, o[4*j+1]*inv, o[4*j+2]*inv, o[4*j+3]*inv);
        *reinterpret_cast<float4*>(op + 4*j) = v;
    }
}

// ---------------------------------------------------------------------------
extern "C" void kernel_launch(void* const* d_in, const int* in_sizes, int n_in,
                              void* d_out, int out_size, void* d_ws, size_t ws_size,
                              hipStream_t stream) {
    const float* x  = (const float*)d_in[0];
    const float* wq = (const float*)d_in[1];
    const float* wk = (const float*)d_in[2];
    const float* wv = (const float*)d_in[3];
    float* out = (float*)d_out;

    unsigned short* qb  = (unsigned short*)d_ws;                   // 2MB
    unsigned short* kb  = qb  + (size_t)ROWS_ * H_;                // 2MB
    unsigned short* vtb = kb  + (size_t)ROWS_ * H_;                // 2MB
    unsigned short* wt  = vtb + (size_t)ROWS_ * H_;                // 384KB

    // chunk size: prefer CH=8 (576 blocks) if workspace allows, else CH=16
    const size_t fixed = (size_t)3*ROWS_*H_*2 + (size_t)3*64*C_*2;
    const size_t need8 = fixed + (size_t)576*8192*2 + (size_t)576*256*4;
    int CH, per_batch;
    if (ws_size >= need8) { CH = 8;  per_batch = 144; }
    else                  { CH = 16; per_batch = 80; }
    const int nblk = 4 * per_batch;

    unsigned short* partO  = wt + (size_t)3*64*C_;
    float*          partML = (float*)(partO + (size_t)nblk*8192);

    // RoPE table (1MB) aliased onto partO: written before qkv, consumed by
    // qkv, then overwritten by attn_chunk. Stream-ordered => deterministic.
    float* rope_tab = (float*)partO;

    prep_kernel<<<560, 256, 0, stream>>>(wq, wk, wv, wt, rope_tab);
    qkv_mfma_kernel<<<ROWS_/64, 512, 0, stream>>>(x, wt, rope_tab, qb, kb, vtb);
    attn_chunk_kernel<<<nblk, 256, 0, stream>>>(qb, kb, vtb, partO, partML,
                                                CH, per_batch);
    combine_kernel<<<256, 256, 0, stream>>>(partO, partML, out, CH, per_batch);
}

// Round 17
// 73.202 us; speedup vs baseline: 1.1668x; 1.1381x over previous
//
#include <hip/hip_runtime.h>
#include <hip/hip_bf16.h>
#include <math.h>

#define B_ 4
#define T_ 4096
#define C_ 1024
#define H_ 64
#define ROWS_ (B_*T_)

typedef __attribute__((ext_vector_type(8))) short bf16x8;
typedef __attribute__((ext_vector_type(4))) float f32x4;

__device__ __forceinline__ unsigned short f2bf(float f) {
    union { float f; unsigned u; } x; x.f = f;
    unsigned r = x.u + 0x7fffu + ((x.u >> 16) & 1u);   // RNE
    return (unsigned short)(r >> 16);
}
__device__ __forceinline__ float bf2f(unsigned short s) {
    union { unsigned u; float f; } x; x.u = ((unsigned)s) << 16;
    return x.f;
}
__device__ __forceinline__ unsigned pk2bf(float a, float b) {
    __hip_bfloat162 h = __float22bfloat162_rn(float2{a, b});
    return *reinterpret_cast<unsigned*>(&h);
}
// async global->LDS DMA, 16B/lane.
__device__ __forceinline__ void gld16(const void* g, void* l) {
    __builtin_amdgcn_global_load_lds(
        (const __attribute__((address_space(1))) unsigned*)g,
        (__attribute__((address_space(3))) unsigned*)l, 16, 0, 0);
}

// ---------------------------------------------------------------------------
// Kernel 0: fused weight prep (blocks 0..47) + RoPE table (blocks 48..559).
// ---------------------------------------------------------------------------
__global__ __launch_bounds__(256) void prep_kernel(
    const float* __restrict__ wq, const float* __restrict__ wk,
    const float* __restrict__ wv, unsigned short* __restrict__ wt,
    float* __restrict__ tab)
{
    __shared__ float ts[64][68];
    const int tid = threadIdx.x;
    if (blockIdx.x < 48) {
        const int m  = blockIdx.x >> 4;
        const int k0 = (blockIdx.x & 15) * 64;
        const float* w = (m == 0) ? wq : (m == 1) ? wk : wv;
        {
            const int r = tid >> 2;
            const int c = (tid & 3) * 16;
            #pragma unroll
            for (int i = 0; i < 4; ++i)
                *reinterpret_cast<float4*>(&ts[r][c + 4*i]) =
                    *reinterpret_cast<const float4*>(&w[(size_t)(k0 + r)*H_ + c + 4*i]);
        }
        __syncthreads();
        {
            const int n  = tid >> 2;
            const int kc = (tid & 3) * 16;
            unsigned short outp[16];
            #pragma unroll
            for (int j = 0; j < 16; ++j) outp[j] = f2bf(ts[kc + j][n]);
            unsigned short* dst = &wt[((size_t)m*64 + n)*C_ + k0 + kc];
            *reinterpret_cast<uint4*>(dst)     = *reinterpret_cast<uint4*>(&outp[0]);
            *reinterpret_cast<uint4*>(dst + 8) = *reinterpret_cast<uint4*>(&outp[8]);
        }
    } else {
        const int idx = (blockIdx.x - 48)*256 + tid;   // 0..131071
        const int t   = idx >> 5;
        const int hp  = idx & 31;
        const float inv = __builtin_exp2f(-(float)hp * (13.287712379549449f / 32.f));
        float sn, cs;
        sincosf((float)t * inv, &sn, &cs);
        *reinterpret_cast<float2*>(&tab[2*idx]) = float2{cs, sn};
    }
}

// ---------------------------------------------------------------------------
// Kernel 1: bf16 MFMA QKV projection + fused table-RoPE. BM=32, 256 thr,
// grid 512 -> 2 blocks/CU resident (LDS 56KB): one block's compute hides
// the other's DMA drain + barrier. W staged via global_load_lds DMA
// double-buffered; x reg-staged 2 steps ahead into double-buffered As.
// ---------------------------------------------------------------------------
__global__ __launch_bounds__(256, 2) void qkv_mfma_kernel(
    const float* __restrict__ x, const unsigned short* __restrict__ wt,
    const float* __restrict__ tab,
    unsigned short* __restrict__ qb, unsigned short* __restrict__ kb,
    unsigned short* __restrict__ vtb)
{
    // bytes: As0 [0,4K) As1 [4K,8K)  Ws0 [8K,32.5K) Ws1 [32.5K,57K)
    __shared__ unsigned short SM[28672];     // 56KB

    const int tid  = threadIdx.x;
    const int w    = tid >> 6;
    const int lane = tid & 63;
    const int rt   = w >> 1;                 // row-tile 0..1
    const int ch   = w & 1;                  // col-half 0..1
    const int lr   = lane & 15;
    const int lg   = lane >> 4;
    const int rb   = blockIdx.x * 32;

    const int ar = tid >> 3;                 // x row 0..31
    const int ac = (tid & 7) * 8;            // fp32 elem col

    float4 axr[2];

    auto load_A = [&](int t) {
        const float* p = &x[(size_t)(rb + ar)*C_ + t*64 + ac];
        axr[0] = *reinterpret_cast<const float4*>(p);
        axr[1] = *reinterpret_cast<const float4*>(p + 4);
    };
    auto write_A = [&](int buf) {
        unsigned tmp[4];
        tmp[0] = pk2bf(axr[0].x, axr[0].y);
        tmp[1] = pk2bf(axr[0].z, axr[0].w);
        tmp[2] = pk2bf(axr[1].x, axr[1].y);
        tmp[3] = pk2bf(axr[1].z, axr[1].w);
        const int off = buf*4096 + ar*128 + ((ac*2) ^ ((ar & 7) << 4));
        *reinterpret_cast<uint4*>((char*)SM + off) = *reinterpret_cast<uint4*>(tmp);
    };
    // W staging via DMA: linear dest slot*16, inverse-swizzled global source.
    auto stage_W = [&](int t, int buf) {
        #pragma unroll
        for (int s = 0; s < 6; ++s) {
            const int slot = s*256 + tid;
            const int r    = slot >> 3;               // n-row 0..191
            const int c8   = (slot & 7) * 8;
            const int c8s  = c8 ^ ((r & 7) << 3);
            gld16(&wt[(size_t)r*C_ + t*64 + c8s],
                  (char*)SM + 8192 + buf*24576 + slot*16);
        }
    };

    f32x4 acc[6];
    #pragma unroll
    for (int j = 0; j < 6; ++j) acc[j] = f32x4{0.f, 0.f, 0.f, 0.f};

    load_A(0);
    stage_W(0, 0);
    write_A(0);
    load_A(1);

    for (int t = 0; t < 16; ++t) {
        const int cur = t & 1, nxt = cur ^ 1;
        __syncthreads();                     // drains Ws[cur] DMA; As[cur] ready
        if (t < 15) { stage_W(t + 1, nxt); write_A(nxt); }
        if (t < 14) load_A(t + 2);
        char* Acur = (char*)SM + cur*4096;
        char* Wcur = (char*)SM + 8192 + cur*24576;
        #pragma unroll
        for (int kh = 0; kh < 2; ++kh) {
            const int arow = rt*16 + lr;
            bf16x8 af = *reinterpret_cast<const bf16x8*>(
                Acur + arow*128 + ((kh*64 + lg*16) ^ ((arow & 7) << 4)));
            #pragma unroll
            for (int j = 0; j < 6; ++j) {
                const int n = ch*96 + j*16 + lr;
                bf16x8 bf = *reinterpret_cast<const bf16x8*>(
                    Wcur + n*128 + ((kh*64 + lg*16) ^ ((n & 7) << 4)));
                acc[j] = __builtin_amdgcn_mfma_f32_16x16x32_bf16(af, bf, acc[j], 0, 0, 0);
            }
        }
    }

    // ---- epilogue: RoPE into LDS tiles (reuse SM), then coalesced stores ---
    // shorts: q [0,2048) k [2048,4096); vT bytes [8192,12288): 64 h x 64B
    __syncthreads();                         // all MFMA LDS reads done
    const int rl0  = rt*16 + lg*4;           // row in block 0..28
    const int row0 = rb + rl0;               // global row
    #pragma unroll
    for (int j = 0; j < 6; ++j) {
        const int c = ch*96 + j*16 + lr;     // 0..191
        const int m = c >> 6;
        const int h = c & 63;
        if (m < 2) {
            const int base_ls = (m == 0) ? 0 : 2048;
            const float qs = (m == 0) ? 0.125f : 1.0f;   // fold softmax scale
            const int hp = h >> 1;
            #pragma unroll
            for (int i = 0; i < 4; ++i) {
                const float v  = acc[j][i];
                const float pr = __shfl_xor(v, 1);
                if (!(h & 1)) {
                    const int tp = (row0 + i) & (T_ - 1);
                    const float2 cssn = *reinterpret_cast<const float2*>(
                        &tab[((size_t)tp*32 + hp)*2]);
                    const float oe = (v*cssn.x - pr*cssn.y) * qs;
                    const float oo = (v*cssn.y + pr*cssn.x) * qs;
                    *reinterpret_cast<unsigned*>(&SM[base_ls + (rl0 + i)*64 + h]) =
                        pk2bf(oe, oo);
                }
            }
        } else {
            unsigned short pk[4];
            #pragma unroll
            for (int i = 0; i < 4; ++i) pk[i] = f2bf(acc[j][i]);
            char* vbase = (char*)SM + 8192 + h*64;
            *reinterpret_cast<uint2*>(vbase + ((rl0*2) ^ ((h & 7) << 3))) =
                *reinterpret_cast<uint2*>(pk);
        }
    }
    __syncthreads();
    {
        // q,k: 32 rows x 64 h, 256 thr x 16B each
        const int row = tid >> 3;            // 0..31
        const int h0  = (tid & 7) * 8;
        *reinterpret_cast<uint4*>(&qb[(size_t)(rb + row)*H_ + h0]) =
            *reinterpret_cast<const uint4*>(&SM[row*64 + h0]);
        *reinterpret_cast<uint4*>(&kb[(size_t)(rb + row)*H_ + h0]) =
            *reinterpret_cast<const uint4*>(&SM[2048 + row*64 + h0]);
        // vT: 64 h x 32 t, thread covers 16B (8 t) of one h row
        const int h  = tid >> 2;             // 0..63
        const int t0 = (tid & 3) * 8;        // 0..24
        char* vbase = (char*)SM + 8192 + h*64;
        uint2 a  = *reinterpret_cast<uint2*>(vbase + (((t0*2)    ) ^ ((h & 7) << 3)));
        uint2 b2 = *reinterpret_cast<uint2*>(vbase + (((t0*2) + 8) ^ ((h & 7) << 3)));
        const int bh  = (rb >> 12)*64 + h;
        const int tp0 = rb & (T_ - 1);
        uint4 o; o.x = a.x; o.y = a.y; o.z = b2.x; o.w = b2.y;
        *reinterpret_cast<uint4*>(&vtb[(size_t)bh*T_ + tp0 + t0]) = o;
    }
}

// ---------------------------------------------------------------------------
// Kernel 2: BQ=128 split-K flash attention — EXACT round-13 best-measured
// config (launch_bounds(256,3)). Wave owns TWO 16-row q-subtiles; K/V frags
// shared across subtiles; waves above diagonal skip steps; DMA dbuf K/V.
// ---------------------------------------------------------------------------
__global__ __launch_bounds__(256, 3) void attn_chunk_kernel(
    const unsigned short* __restrict__ qb, const unsigned short* __restrict__ kb,
    const unsigned short* __restrict__ vtb,
    unsigned short* __restrict__ partO, float* __restrict__ partML,
    int CH, int per_batch)
{
    __shared__ unsigned short Kls[2][4096];
    __shared__ unsigned short Vls[2][4096];
    __shared__ unsigned short Pls[4][2048];

    const int tid  = threadIdx.x;
    const int w    = tid >> 6;       // wave 0..3, owns q-rows w*32..w*32+31
    const int lane = tid & 63;
    const int lr   = lane & 15;
    const int lg   = lane >> 4;

    const int cid = blockIdx.x;
    const int b   = cid / per_batch;
    int r0 = cid - b*per_batch;
    const int G = CH >> 1;
    int a = 0, off = 0;
    while (r0 >= off + G*(a + 1)) { off += G*(a + 1); ++a; }
    const int idx = r0 - off;
    const int qt  = G*a + idx/(a + 1);   // 128-row q-tile, 0..31
    const int c   = idx % (a + 1);

    const int q0  = qt * 128;
    const int kt0 = c * CH;
    const int ntk = 2*qt + 2;
    const int ns  = min(kt0 + CH, ntk) - kt0;
    const size_t rbase = (size_t)b * T_;
    const int dtile = 2*qt + (w >> 1);   // wave-uniform diagonal k-tile

    char* Pw = (char*)&Pls[w][0];

    bf16x8 qf[2][2];
    #pragma unroll
    for (int s16 = 0; s16 < 2; ++s16) {
        const unsigned short* qp = qb + (rbase + q0 + w*32 + s16*16 + lr)*H_ + lg*8;
        qf[s16][0] = *reinterpret_cast<const bf16x8*>(qp);
        qf[s16][1] = *reinterpret_cast<const bf16x8*>(qp + 32);
    }

    float mrow[2] = {-1e30f, -1e30f};
    float lrow[2] = {0.f, 0.f};
    f32x4 acc[2][4];
    #pragma unroll
    for (int s16 = 0; s16 < 2; ++s16)
        #pragma unroll
        for (int hs = 0; hs < 4; ++hs) acc[s16][hs] = f32x4{0.f, 0.f, 0.f, 0.f};

    const int srow = tid >> 3;           // 0..31
    const int scol = (tid & 7) * 8;      // elem col
    auto stage_dma = [&](int kt, int buf) {
        #pragma unroll
        for (int s = 0; s < 2; ++s) {
            const int r    = s*32 + srow;
            const int c8s  = scol ^ ((r & 7) << 3);
            const int slot = s*256 + tid;
            gld16(&kb[(rbase + (size_t)kt*64 + r)*H_ + c8s],
                  (char*)&Kls[buf][0] + slot*16);
            gld16(&vtb[((size_t)(b*64 + r))*T_ + (size_t)kt*64 + c8s],
                  (char*)&Vls[buf][0] + slot*16);
        }
    };

    stage_dma(kt0, 0);

    for (int s = 0; s < ns; ++s) {
        __syncthreads();                 // buf s&1 DMA drained + prior reads done
        if (s + 1 < ns) stage_dma(kt0 + s + 1, (s + 1) & 1);
        const int kt = kt0 + s;
        char* Kb = (char*)&Kls[s & 1][0];
        char* Vb = (char*)&Vls[s & 1][0];

        if (kt <= dtile) {               // wave-uniform causal skip
            f32x4 st[2][4];
            __builtin_amdgcn_s_setprio(1);
            #pragma unroll
            for (int ks = 0; ks < 4; ++ks) {
                const int rr2 = ks*16 + lr;
                const int sw  = (rr2 & 7) << 4;
                bf16x8 kf0 = *reinterpret_cast<const bf16x8*>(Kb + rr2*128 + ((lg*16     ) ^ sw));
                bf16x8 kf1 = *reinterpret_cast<const bf16x8*>(Kb + rr2*128 + ((lg*16 + 64) ^ sw));
                #pragma unroll
                for (int s16 = 0; s16 < 2; ++s16) {
                    f32x4 t = {0.f, 0.f, 0.f, 0.f};
                    t = __builtin_amdgcn_mfma_f32_16x16x32_bf16(kf0, qf[s16][0], t, 0, 0, 0);
                    t = __builtin_amdgcn_mfma_f32_16x16x32_bf16(kf1, qf[s16][1], t, 0, 0, 0);
                    st[s16][ks] = t;
                }
            }
            __builtin_amdgcn_s_setprio(0);

            float scl[2];
            const int swp = (lr & 7) << 4;
            #pragma unroll
            for (int s16 = 0; s16 < 2; ++s16) {
                const int qg = q0 + w*32 + s16*16 + lr;
                float mx = -1e30f;
                if (kt == dtile) {
                    #pragma unroll
                    for (int ks = 0; ks < 4; ++ks)
                        #pragma unroll
                        for (int i = 0; i < 4; ++i) {
                            const int kg = kt*64 + ks*16 + lg*4 + i;
                            const float v = (kg <= qg) ? st[s16][ks][i] : -1e30f;
                            st[s16][ks][i] = v;
                            mx = fmaxf(mx, v);
                        }
                } else {
                    #pragma unroll
                    for (int ks = 0; ks < 4; ++ks)
                        #pragma unroll
                        for (int i = 0; i < 4; ++i) mx = fmaxf(mx, st[s16][ks][i]);
                }
                mx = fmaxf(mx, __shfl_xor(mx, 16));
                mx = fmaxf(mx, __shfl_xor(mx, 32));
                const float mn = fmaxf(mrow[s16], mx);
                scl[s16] = __expf(mrow[s16] - mn);
                float ls = 0.f;
                #pragma unroll
                for (int ks = 0; ks < 4; ++ks)
                    #pragma unroll
                    for (int i = 0; i < 4; ++i) {
                        const float p = __expf(st[s16][ks][i] - mn);
                        st[s16][ks][i] = p;
                        ls += p;
                    }
                ls += __shfl_xor(ls, 16);
                ls += __shfl_xor(ls, 32);
                lrow[s16] = lrow[s16]*scl[s16] + ls;
                mrow[s16] = mn;

                const int pr = s16*16 + lr;
                #pragma unroll
                for (int ks = 0; ks < 4; ++ks) {
                    const unsigned u0 = pk2bf(st[s16][ks][0], st[s16][ks][1]);
                    const unsigned u1 = pk2bf(st[s16][ks][2], st[s16][ks][3]);
                    *reinterpret_cast<uint2*>(Pw + pr*128 + ((ks*32 + lg*8) ^ swp)) =
                        make_uint2(u0, u1);
                }
            }

            #pragma unroll
            for (int s16 = 0; s16 < 2; ++s16) {
                float sclr[4];
                #pragma unroll
                for (int i = 0; i < 4; ++i) sclr[i] = __shfl(scl[s16], lg*4 + i);
                #pragma unroll
                for (int hs = 0; hs < 4; ++hs)
                    #pragma unroll
                    for (int i = 0; i < 4; ++i) acc[s16][hs][i] *= sclr[i];
            }

            bf16x8 pf[2][2];
            #pragma unroll
            for (int s16 = 0; s16 < 2; ++s16) {
                const int pr = s16*16 + lr;
                pf[s16][0] = *reinterpret_cast<const bf16x8*>(Pw + pr*128 + ((lg*16     ) ^ swp));
                pf[s16][1] = *reinterpret_cast<const bf16x8*>(Pw + pr*128 + ((lg*16 + 64) ^ swp));
            }
            __builtin_amdgcn_s_setprio(1);
            #pragma unroll
            for (int hs = 0; hs < 4; ++hs) {
                const int rv  = hs*16 + lr;
                const int swv = (rv & 7) << 4;
                bf16x8 vf0 = *reinterpret_cast<const bf16x8*>(Vb + rv*128 + ((lg*16     ) ^ swv));
                bf16x8 vf1 = *reinterpret_cast<const bf16x8*>(Vb + rv*128 + ((lg*16 + 64) ^ swv));
                #pragma unroll
                for (int s16 = 0; s16 < 2; ++s16) {
                    acc[s16][hs] = __builtin_amdgcn_mfma_f32_16x16x32_bf16(pf[s16][0], vf0, acc[s16][hs], 0, 0, 0);
                    acc[s16][hs] = __builtin_amdgcn_mfma_f32_16x16x32_bf16(pf[s16][1], vf1, acc[s16][hs], 0, 0, 0);
                }
            }
            __builtin_amdgcn_s_setprio(0);
        }
    }

    #pragma unroll
    for (int s16 = 0; s16 < 2; ++s16) {
        const int myrow = w*32 + s16*16 + lr;
        if (lg == 0) {
            partML[(size_t)cid*256 + myrow]       = mrow[s16];
            partML[(size_t)cid*256 + 128 + myrow] = lrow[s16];
        }
    }
    __syncthreads();                          // all LDS use done, reuse Kls
    unsigned short* Ols = &Kls[0][0];         // 16KB: [128 rows][64 h]
    #pragma unroll
    for (int s16 = 0; s16 < 2; ++s16)
        #pragma unroll
        for (int hs = 0; hs < 4; ++hs)
            #pragma unroll
            for (int i = 0; i < 4; ++i)
                Ols[(w*32 + s16*16 + lg*4 + i)*64 + hs*16 + lr] =
                    f2bf(acc[s16][hs][i]);
    __syncthreads();
    {
        const int e0 = tid * 32;              // 8192 elems / 256 thr
        #pragma unroll
        for (int j = 0; j < 4; ++j)
            *reinterpret_cast<uint4*>(&partO[(size_t)cid*8192 + e0 + 8*j]) =
                *reinterpret_cast<const uint4*>(&Ols[e0 + 8*j]);
    }
}

// ---------------------------------------------------------------------------
// Kernel 3: combine partials per (b, 128-row q-tile, half). 256 blocks.
// ---------------------------------------------------------------------------
__global__ __launch_bounds__(256) void combine_kernel(
    const unsigned short* __restrict__ partO, const float* __restrict__ partML,
    float* __restrict__ out, int CH, int per_batch)
{
    const int bq   = blockIdx.x;          // b(2b) | qt(5b) | half(1b)
    const int b    = bq >> 6;
    const int qt   = (bq >> 1) & 31;
    const int half = bq & 1;
    const int G  = CH >> 1;
    const int a  = qt / G;
    const int nc = a + 1;                 // <= 8
    const int cb = b*per_batch + (G*a*(a + 1))/2 + (qt - G*a)*(a + 1);

    const int tid = threadIdx.x;
    const int row = half*64 + (tid >> 2); // 0..127 within tile
    const int h0  = (tid & 3) * 16;

    float mi[8], wi[8];
    float M = -1e30f;
    #pragma unroll
    for (int i = 0; i < 8; ++i) if (i < nc) {
        mi[i] = partML[(size_t)(cb + i)*256 + row];
        M = fmaxf(M, mi[i]);
    }
    float L = 0.f;
    #pragma unroll
    for (int i = 0; i < 8; ++i) if (i < nc) {
        wi[i] = __expf(mi[i] - M);
        L += partML[(size_t)(cb + i)*256 + 128 + row] * wi[i];
    }
    const float inv = 1.f / L;

    float o[16];
    #pragma unroll
    for (int j = 0; j < 16; ++j) o[j] = 0.f;
    #pragma unroll
    for (int i = 0; i < 8; ++i) if (i < nc) {
        const unsigned short* p = &partO[(size_t)(cb + i)*8192 + (size_t)row*64 + h0];
        uint4 u0 = *reinterpret_cast<const uint4*>(p);
        uint4 u1 = *reinterpret_cast<const uint4*>(p + 8);
        const unsigned* uu = (const unsigned*)&u0;
        #pragma unroll
        for (int j = 0; j < 4; ++j) {
            o[2*j]   += bf2f((unsigned short)(uu[j] & 0xffffu)) * wi[i];
            o[2*j+1] += bf2f((unsigned short)(uu[j] >> 16))     * wi[i];
        }
        const unsigned* uv = (const unsigned*)&u1;
        #pragma unroll
        for (int j = 0; j < 4; ++j) {
            o[8+2*j]   += bf2f((unsigned short)(uv[j] & 0xffffu)) * wi[i];
            o[8+2*j+1] += bf2f((unsigned short)(uv[j] >> 16))     * wi[i];
        }
    }
    float* op = &out[((size_t)b*T_ + (size_t)qt*128 + row)*H_ + h0];
    #pragma unroll
    for (int j = 0; j < 4; ++j) {
        float4 v = make_float4(o[4*j]*inv, o[4*j+1]*inv, o[4*j+2]*inv, o[4*j+3]*inv);
        *reinterpret_cast<float4*>(op + 4*j) = v;
    }
}

// ---------------------------------------------------------------------------
extern "C" void kernel_launch(void* const* d_in, const int* in_sizes, int n_in,
                              void* d_out, int out_size, void* d_ws, size_t ws_size,
                              hipStream_t stream) {
    const float* x  = (const float*)d_in[0];
    const float* wq = (const float*)d_in[1];
    const float* wk = (const float*)d_in[2];
    const float* wv = (const float*)d_in[3];
    float* out = (float*)d_out;

    unsigned short* qb  = (unsigned short*)d_ws;                   // 2MB
    unsigned short* kb  = qb  + (size_t)ROWS_ * H_;                // 2MB
    unsigned short* vtb = kb  + (size_t)ROWS_ * H_;                // 2MB
    unsigned short* wt  = vtb + (size_t)ROWS_ * H_;                // 384KB

    // chunk size: prefer CH=8 (576 blocks) if workspace allows, else CH=16
    const size_t fixed = (size_t)3*ROWS_*H_*2 + (size_t)3*64*C_*2;
    const size_t need8 = fixed + (size_t)576*8192*2 + (size_t)576*256*4;
    int CH, per_batch;
    if (ws_size >= need8) { CH = 8;  per_batch = 144; }
    else                  { CH = 16; per_batch = 80; }
    const int nblk = 4 * per_batch;

    unsigned short* partO  = wt + (size_t)3*64*C_;
    float*          partML = (float*)(partO + (size_t)nblk*8192);

    // RoPE table (1MB) aliased onto partO: written before qkv, consumed by
    // qkv, then overwritten by attn_chunk. Stream-ordered => deterministic.
    float* rope_tab = (float*)partO;

    prep_kernel<<<560, 256, 0, stream>>>(wq, wk, wv, wt, rope_tab);
    qkv_mfma_kernel<<<ROWS_/32, 256, 0, stream>>>(x, wt, rope_tab, qb, kb, vtb);
    attn_chunk_kernel<<<nblk, 256, 0, stream>>>(qb, kb, vtb, partO, partML,
                                                CH, per_batch);
    combine_kernel<<<256, 256, 0, stream>>>(partO, partML, out, CH, per_batch);
}